// Round 1
// baseline (151.087 us; speedup 1.0000x reference)
//
#include <hip/hip_runtime.h>
#include <math.h>

// DynamicNTXentLoss on MI355X.
// Inputs: zis (65536,256) f32, zjs (65536,256) f32, soft_labels (4,3) f32.
// Output: scalar f32 loss.
//
// Per group g (nc = n/2 groups):
//   r0 = zjs[2g], r1 = zjs[2g+1], r2 = zis[2g], r3 = zis[2g+1]
//   normalize, sim_ij = dot(ri,rj)/(|ri||rj|)   (|.| clamped at 1e-8)
//   logits rows (x2 for 1/T, T=0.5):
//     row0: [s02, s01, s03]
//     row1: [s13, s01, s12]
//     row2: [s02, s12, s23]
//     row3: [s13, s03, s23]
//   loss += sum_k soft_labels[i][k] * (lse_i - l_ik);  final / (2n)

constexpr int D = 256;

__device__ __forceinline__ float dot4(float4 a, float4 b) {
    return a.x * b.x + a.y * b.y + a.z * b.z + a.w * b.w;
}

__device__ __forceinline__ float wred(float x) {
#pragma unroll
    for (int off = 1; off < 64; off <<= 1) x += __shfl_xor(x, off, 64);
    return x;
}

// weighted -(logp) for one row: logits (a,b,c), weights (s0,s1,s2)
__device__ __forceinline__ float rowloss(float a, float b, float c,
                                         float s0, float s1, float s2) {
    float m = fmaxf(fmaxf(a, b), c);
    float lse = m + logf(expf(a - m) + expf(b - m) + expf(c - m));
    return s0 * (lse - a) + s1 * (lse - b) + s2 * (lse - c);
}

__global__ __launch_bounds__(256) void ntxent_stage1(
    const float* __restrict__ zis, const float* __restrict__ zjs,
    const float* __restrict__ sl, float* __restrict__ partial, int nc) {
    const int lane = threadIdx.x & 63;
    const int wid  = threadIdx.x >> 6;
    const int wpb  = blockDim.x >> 6;
    const int gw   = blockIdx.x * wpb + wid;
    const int nw   = gridDim.x * wpb;

    // soft labels: 12 uniform scalar loads (L2/sL1 cached)
    const float sl00 = sl[0],  sl01 = sl[1],  sl02 = sl[2];
    const float sl10 = sl[3],  sl11 = sl[4],  sl12 = sl[5];
    const float sl20 = sl[6],  sl21 = sl[7],  sl22 = sl[8];
    const float sl30 = sl[9],  sl31 = sl[10], sl32 = sl[11];

    float wsum = 0.0f;
    for (int g = gw; g < nc; g += nw) {
        const float4* r0 = (const float4*)(zjs + (size_t)(2 * g) * D);
        const float4* r1 = (const float4*)(zjs + (size_t)(2 * g + 1) * D);
        const float4* r2 = (const float4*)(zis + (size_t)(2 * g) * D);
        const float4* r3 = (const float4*)(zis + (size_t)(2 * g + 1) * D);
        float4 v0 = r0[lane];
        float4 v1 = r1[lane];
        float4 v2 = r2[lane];
        float4 v3 = r3[lane];

        float n0 = dot4(v0, v0), n1 = dot4(v1, v1);
        float n2 = dot4(v2, v2), n3 = dot4(v3, v3);
        float d01 = dot4(v0, v1), d02 = dot4(v0, v2), d03 = dot4(v0, v3);
        float d12 = dot4(v1, v2), d13 = dot4(v1, v3), d23 = dot4(v2, v3);

        n0 = wred(n0);  n1 = wred(n1);  n2 = wred(n2);  n3 = wred(n3);
        d01 = wred(d01); d02 = wred(d02); d03 = wred(d03);
        d12 = wred(d12); d13 = wred(d13); d23 = wred(d23);

        const float i0 = 1.0f / fmaxf(sqrtf(n0), 1e-8f);
        const float i1 = 1.0f / fmaxf(sqrtf(n1), 1e-8f);
        const float i2 = 1.0f / fmaxf(sqrtf(n2), 1e-8f);
        const float i3 = 1.0f / fmaxf(sqrtf(n3), 1e-8f);

        // fold 1/T = 2 into the sims
        const float s01 = 2.0f * d01 * i0 * i1;
        const float s02 = 2.0f * d02 * i0 * i2;
        const float s03 = 2.0f * d03 * i0 * i3;
        const float s12 = 2.0f * d12 * i1 * i2;
        const float s13 = 2.0f * d13 * i1 * i3;
        const float s23 = 2.0f * d23 * i2 * i3;

        float gl = 0.0f;
        gl += rowloss(s02, s01, s03, sl00, sl01, sl02);
        gl += rowloss(s13, s01, s12, sl10, sl11, sl12);
        gl += rowloss(s02, s12, s23, sl20, sl21, sl22);
        gl += rowloss(s13, s03, s23, sl30, sl31, sl32);
        wsum += gl;
    }

    __shared__ float smem[8];
    if (lane == 0) smem[wid] = wsum;
    __syncthreads();
    if (threadIdx.x == 0) {
        float b = 0.0f;
        for (int i = 0; i < wpb; ++i) b += smem[i];
        partial[blockIdx.x] = b;
    }
}

__global__ __launch_bounds__(256) void ntxent_stage2(
    const float* __restrict__ partial, int nparts, double inv_div,
    float* __restrict__ out) {
    double acc = 0.0;
    for (int i = threadIdx.x; i < nparts; i += 256) acc += (double)partial[i];
#pragma unroll
    for (int off = 1; off < 64; off <<= 1) acc += __shfl_xor(acc, off, 64);
    __shared__ double sm[4];
    const int wid = threadIdx.x >> 6;
    if ((threadIdx.x & 63) == 0) sm[wid] = acc;
    __syncthreads();
    if (threadIdx.x == 0) {
        double t = sm[0] + sm[1] + sm[2] + sm[3];
        out[0] = (float)(t * inv_div);
    }
}

extern "C" void kernel_launch(void* const* d_in, const int* in_sizes, int n_in,
                              void* d_out, int out_size, void* d_ws, size_t ws_size,
                              hipStream_t stream) {
    const float* zis = (const float*)d_in[0];
    const float* zjs = (const float*)d_in[1];
    const float* sl  = (const float*)d_in[2];
    float* out = (float*)d_out;
    float* partial = (float*)d_ws;

    const int n  = in_sizes[0] / D;   // 65536 rows
    const int nc = n / 2;             // 32768 groups

    const int blocks = 2048;          // 8192 waves, 4 groups/wave
    ntxent_stage1<<<blocks, 256, 0, stream>>>(zis, zjs, sl, partial, nc);

    const double inv_div = 1.0 / (2.0 * (double)n);
    ntxent_stage2<<<1, 256, 0, stream>>>(partial, blocks, inv_div, out);
}

// Round 2
// 148.643 us; speedup vs baseline: 1.0164x; 1.0164x over previous
//
#include <hip/hip_runtime.h>
#include <math.h>

// DynamicNTXentLoss on MI355X — r2: 16-lanes-per-group layout.
// Inputs: zis (65536,256) f32, zjs (65536,256) f32, soft_labels (4,3) f32.
// Output: scalar f32 loss.
//
// Per group g (nc = n/2):
//   r0 = zjs[2g], r1 = zjs[2g+1], r2 = zis[2g], r3 = zis[2g+1]
//   sims s_ij on normalized rows (norm clamped 1e-8), logits ×2 (1/T):
//     row0: [s02, s01, s03]  row1: [s13, s01, s12]
//     row2: [s02, s12, s23]  row3: [s13, s03, s23]
//   loss += Σ_k sl[i][k] * (lse_i - l_ik);  final / (2n)
//
// Layout: wave of 64 = 4 subgroups × 16 lanes. Subgroup q handles group
// (quad*4 + q). Lane t∈[0,16) owns floats [t*4 + c*64, +4) for c=0..3 of
// each of the 4 rows → per-lane partial dots, then 4-step __shfl_xor
// (masks 1,2,4,8 stay inside the 16-lane subgroup). One instruction
// stream serves 4 groups at once.

constexpr int D = 256;

__device__ __forceinline__ float dot4(float4 a, float4 b) {
    return fmaf(a.x, b.x, fmaf(a.y, b.y, fmaf(a.z, b.z, a.w * b.w)));
}

// reduce across the 16-lane subgroup
__device__ __forceinline__ float red16(float x) {
    x += __shfl_xor(x, 1);
    x += __shfl_xor(x, 2);
    x += __shfl_xor(x, 4);
    x += __shfl_xor(x, 8);
    return x;
}

__device__ __forceinline__ float rowloss(float a, float b, float c,
                                         float s0, float s1, float s2) {
    float m = fmaxf(fmaxf(a, b), c);
    float lse = m + logf(expf(a - m) + expf(b - m) + expf(c - m));
    return s0 * (lse - a) + s1 * (lse - b) + s2 * (lse - c);
}

__global__ __launch_bounds__(256) void ntxent_stage1(
    const float* __restrict__ zis, const float* __restrict__ zjs,
    const float* __restrict__ sl, float* __restrict__ partial, int nc) {
    const int lane = threadIdx.x & 63;
    const int wid  = threadIdx.x >> 6;      // wave in block (0..3)
    const int t    = lane & 15;             // lane in subgroup
    const int q    = lane >> 4;             // subgroup (group-in-wave)

    const int gwave = blockIdx.x * 4 + wid; // global wave id
    const int nwave = gridDim.x * 4;
    const int nquad = (nc + 3) >> 2;        // group-quads

    const float sl00 = sl[0],  sl01 = sl[1],  sl02 = sl[2];
    const float sl10 = sl[3],  sl11 = sl[4],  sl12 = sl[5];
    const float sl20 = sl[6],  sl21 = sl[7],  sl22 = sl[8];
    const float sl30 = sl[9],  sl31 = sl[10], sl32 = sl[11];

    float wsum = 0.0f;
    for (int quad = gwave; quad < nquad; quad += nwave) {
        const int g = quad * 4 + q;
        const bool valid = g < nc;
        const int gc = valid ? g : 0;

        const float* rj = zjs + (size_t)(2 * gc) * D;  // rows 0,1
        const float* ri = zis + (size_t)(2 * gc) * D;  // rows 2,3
        const int o = t * 4;

        // 16 independent 16B loads up-front (max MLP)
        float4 v0[4], v1[4], v2[4], v3[4];
#pragma unroll
        for (int c = 0; c < 4; ++c) {
            v0[c] = *(const float4*)(rj + c * 64 + o);
            v1[c] = *(const float4*)(rj + D + c * 64 + o);
            v2[c] = *(const float4*)(ri + c * 64 + o);
            v3[c] = *(const float4*)(ri + D + c * 64 + o);
        }

        float n0 = 0, n1 = 0, n2 = 0, n3 = 0;
        float d01 = 0, d02 = 0, d03 = 0, d12 = 0, d13 = 0, d23 = 0;
#pragma unroll
        for (int c = 0; c < 4; ++c) {
            n0 += dot4(v0[c], v0[c]);  n1 += dot4(v1[c], v1[c]);
            n2 += dot4(v2[c], v2[c]);  n3 += dot4(v3[c], v3[c]);
            d01 += dot4(v0[c], v1[c]); d02 += dot4(v0[c], v2[c]);
            d03 += dot4(v0[c], v3[c]); d12 += dot4(v1[c], v2[c]);
            d13 += dot4(v1[c], v3[c]); d23 += dot4(v2[c], v3[c]);
        }

        n0 = red16(n0);  n1 = red16(n1);  n2 = red16(n2);  n3 = red16(n3);
        d01 = red16(d01); d02 = red16(d02); d03 = red16(d03);
        d12 = red16(d12); d13 = red16(d13); d23 = red16(d23);

        const float i0 = 1.0f / fmaxf(sqrtf(n0), 1e-8f);
        const float i1 = 1.0f / fmaxf(sqrtf(n1), 1e-8f);
        const float i2 = 1.0f / fmaxf(sqrtf(n2), 1e-8f);
        const float i3 = 1.0f / fmaxf(sqrtf(n3), 1e-8f);

        // fold 1/T = 2
        const float s01 = 2.0f * d01 * i0 * i1;
        const float s02 = 2.0f * d02 * i0 * i2;
        const float s03 = 2.0f * d03 * i0 * i3;
        const float s12 = 2.0f * d12 * i1 * i2;
        const float s13 = 2.0f * d13 * i1 * i3;
        const float s23 = 2.0f * d23 * i2 * i3;

        float gl = 0.0f;
        gl += rowloss(s02, s01, s03, sl00, sl01, sl02);
        gl += rowloss(s13, s01, s12, sl10, sl11, sl12);
        gl += rowloss(s02, s12, s23, sl20, sl21, sl22);
        gl += rowloss(s13, s03, s23, sl30, sl31, sl32);
        if (valid) wsum += gl;          // all 16 lanes of subgroup add gl
    }
    wsum *= 0.0625f;                    // /16: subgroup lanes were redundant

    // 64-lane reduce (once per wave, cost negligible)
#pragma unroll
    for (int off = 1; off < 64; off <<= 1) wsum += __shfl_xor(wsum, off);

    __shared__ float smem[4];
    if (lane == 0) smem[wid] = wsum;
    __syncthreads();
    if (threadIdx.x == 0)
        partial[blockIdx.x] = smem[0] + smem[1] + smem[2] + smem[3];
}

__global__ __launch_bounds__(256) void ntxent_stage2(
    const float* __restrict__ partial, int nparts, double inv_div,
    float* __restrict__ out) {
    double acc = 0.0;
    for (int i = threadIdx.x; i < nparts; i += 256) acc += (double)partial[i];
#pragma unroll
    for (int off = 1; off < 64; off <<= 1) acc += __shfl_xor(acc, off);
    __shared__ double sm[4];
    const int wid = threadIdx.x >> 6;
    if ((threadIdx.x & 63) == 0) sm[wid] = acc;
    __syncthreads();
    if (threadIdx.x == 0) out[0] = (float)((sm[0] + sm[1] + sm[2] + sm[3]) * inv_div);
}

extern "C" void kernel_launch(void* const* d_in, const int* in_sizes, int n_in,
                              void* d_out, int out_size, void* d_ws, size_t ws_size,
                              hipStream_t stream) {
    const float* zis = (const float*)d_in[0];
    const float* zjs = (const float*)d_in[1];
    const float* sl  = (const float*)d_in[2];
    float* out = (float*)d_out;
    float* partial = (float*)d_ws;

    const int n  = in_sizes[0] / D;   // 65536 rows
    const int nc = n / 2;             // 32768 groups

    // 2048 blocks × 4 waves = 8192 waves; 4 groups/wave-iter → exactly
    // one iteration per wave at nc=32768.
    const int blocks = 2048;
    ntxent_stage1<<<blocks, 256, 0, stream>>>(zis, zjs, sl, partial, nc);

    const double inv_div = 1.0 / (2.0 * (double)n);
    ntxent_stage2<<<1, 256, 0, stream>>>(partial, blocks, inv_div, out);
}

// Round 4
// 147.141 us; speedup vs baseline: 1.0268x; 1.0102x over previous
//
#include <hip/hip_runtime.h>
#include <math.h>

// DynamicNTXentLoss on MI355X — r3: DPP reductions + full-MLP loads.
// Inputs: zis (65536,256) f32, zjs (65536,256) f32, soft_labels (4,3) f32.
// Output: scalar f32 loss.
//
// Layout: wave = 4 subgroups x 16 lanes; subgroup q handles group quad*4+q.
// Lane t owns floats [t*4 + c*64, +4), c=0..3, of each of the group's 4 rows.
// All 16 loads are issued before any FMA (VGPR budget 128 via
// __launch_bounds__(256,4) — r2's 60-VGPR build forced load serialization).
// 16-lane reductions are DPP v_add chains (VALU pipe) instead of
// ds_swizzle shuffles (LDS pipe + lgkm waits).

constexpr int D = 256;

__device__ __forceinline__ float dot4(float4 a, float4 b) {
    return fmaf(a.x, b.x, fmaf(a.y, b.y, fmaf(a.z, b.z, a.w * b.w)));
}

template <int CTRL>
__device__ __forceinline__ float dpp_add(float x) {
    int y = __builtin_amdgcn_update_dpp(0, __float_as_int(x), CTRL, 0xF, 0xF, true);
    return x + __int_as_float(y);
}

// sum across the 16-lane row; all 16 lanes receive the total
__device__ __forceinline__ float red16(float x) {
    x = dpp_add<0xB1>(x);   // quad_perm [1,0,3,2]  (xor 1)
    x = dpp_add<0x4E>(x);   // quad_perm [2,3,0,1]  (xor 2)
    x = dpp_add<0x124>(x);  // row_ror:4
    x = dpp_add<0x128>(x);  // row_ror:8
    return x;
}

__device__ __forceinline__ float rowloss(float a, float b, float c,
                                         float s0, float s1, float s2) {
    float m = fmaxf(fmaxf(a, b), c);
    float lse = m + __logf(__expf(a - m) + __expf(b - m) + __expf(c - m));
    return s0 * (lse - a) + s1 * (lse - b) + s2 * (lse - c);
}

__global__ __launch_bounds__(256, 4) void ntxent_stage1(
    const float* __restrict__ zis, const float* __restrict__ zjs,
    const float* __restrict__ sl, float* __restrict__ partial, int nc) {
    const int lane = threadIdx.x & 63;
    const int wid  = threadIdx.x >> 6;
    const int t    = lane & 15;
    const int q    = lane >> 4;

    const int gwave = blockIdx.x * 4 + wid;
    const int nwave = gridDim.x * 4;
    const int nquad = (nc + 3) >> 2;

    const float sl00 = sl[0],  sl01 = sl[1],  sl02 = sl[2];
    const float sl10 = sl[3],  sl11 = sl[4],  sl12 = sl[5];
    const float sl20 = sl[6],  sl21 = sl[7],  sl22 = sl[8];
    const float sl30 = sl[9],  sl31 = sl[10], sl32 = sl[11];

    float wsum = 0.0f;
    for (int quad = gwave; quad < nquad; quad += nwave) {
        const int g = quad * 4 + q;
        const bool valid = g < nc;
        const int gc = valid ? g : 0;

        const float* rj = zjs + (size_t)(2 * gc) * D;
        const float* ri = zis + (size_t)(2 * gc) * D;
        const int o = t * 4;

        // all 16 independent 16B loads issued before any consumption
        float4 v[16];
#pragma unroll
        for (int c = 0; c < 4; ++c) {
            v[c]      = *(const float4*)(rj + c * 64 + o);
            v[4 + c]  = *(const float4*)(rj + D + c * 64 + o);
            v[8 + c]  = *(const float4*)(ri + c * 64 + o);
            v[12 + c] = *(const float4*)(ri + D + c * 64 + o);
        }

        float n0 = 0, n1 = 0, n2 = 0, n3 = 0;
        float d01 = 0, d02 = 0, d03 = 0, d12 = 0, d13 = 0, d23 = 0;
#pragma unroll
        for (int c = 0; c < 4; ++c) {
            const float4 a = v[c], b = v[4 + c], cc = v[8 + c], d = v[12 + c];
            n0 += dot4(a, a);   n1 += dot4(b, b);
            n2 += dot4(cc, cc); n3 += dot4(d, d);
            d01 += dot4(a, b);  d02 += dot4(a, cc);
            d03 += dot4(a, d);  d12 += dot4(b, cc);
            d13 += dot4(b, d);  d23 += dot4(cc, d);
        }

        n0 = red16(n0);  n1 = red16(n1);  n2 = red16(n2);  n3 = red16(n3);
        d01 = red16(d01); d02 = red16(d02); d03 = red16(d03);
        d12 = red16(d12); d13 = red16(d13); d23 = red16(d23);

        const float i0 = 1.0f / fmaxf(sqrtf(n0), 1e-8f);
        const float i1 = 1.0f / fmaxf(sqrtf(n1), 1e-8f);
        const float i2 = 1.0f / fmaxf(sqrtf(n2), 1e-8f);
        const float i3 = 1.0f / fmaxf(sqrtf(n3), 1e-8f);

        // fold 1/T = 2
        const float s01 = 2.0f * d01 * i0 * i1;
        const float s02 = 2.0f * d02 * i0 * i2;
        const float s03 = 2.0f * d03 * i0 * i3;
        const float s12 = 2.0f * d12 * i1 * i2;
        const float s13 = 2.0f * d13 * i1 * i3;
        const float s23 = 2.0f * d23 * i2 * i3;

        float gl = 0.0f;
        gl += rowloss(s02, s01, s03, sl00, sl01, sl02);
        gl += rowloss(s13, s01, s12, sl10, sl11, sl12);
        gl += rowloss(s02, s12, s23, sl20, sl21, sl22);
        gl += rowloss(s13, s03, s23, sl30, sl31, sl32);
        if (valid) wsum += gl;
    }
    wsum *= 0.0625f;   // 16 redundant lanes per subgroup

#pragma unroll
    for (int off = 1; off < 64; off <<= 1) wsum += __shfl_xor(wsum, off);

    __shared__ float smem[4];
    if (lane == 0) smem[wid] = wsum;
    __syncthreads();
    if (threadIdx.x == 0)
        partial[blockIdx.x] = smem[0] + smem[1] + smem[2] + smem[3];
}

__global__ __launch_bounds__(256) void ntxent_stage2(
    const float* __restrict__ partial, int nparts, double inv_div,
    float* __restrict__ out) {
    double acc = 0.0;
    for (int i = threadIdx.x; i < nparts; i += 256) acc += (double)partial[i];
#pragma unroll
    for (int off = 1; off < 64; off <<= 1) acc += __shfl_xor(acc, off);
    __shared__ double sm[4];
    const int wid = threadIdx.x >> 6;
    if ((threadIdx.x & 63) == 0) sm[wid] = acc;
    __syncthreads();
    if (threadIdx.x == 0) out[0] = (float)((sm[0] + sm[1] + sm[2] + sm[3]) * inv_div);
}

extern "C" void kernel_launch(void* const* d_in, const int* in_sizes, int n_in,
                              void* d_out, int out_size, void* d_ws, size_t ws_size,
                              hipStream_t stream) {
    const float* zis = (const float*)d_in[0];
    const float* zjs = (const float*)d_in[1];
    const float* sl  = (const float*)d_in[2];
    float* out = (float*)d_out;
    float* partial = (float*)d_ws;

    const int n  = in_sizes[0] / D;   // 65536 rows
    const int nc = n / 2;             // 32768 groups

    const int blocks = 2048;          // 8192 waves, 1 quad (4 groups) each
    ntxent_stage1<<<blocks, 256, 0, stream>>>(zis, zjs, sl, partial, nc);

    const double inv_div = 1.0 / (2.0 * (double)n);
    ntxent_stage2<<<1, 256, 0, stream>>>(partial, blocks, inv_div, out);
}